// Round 12
// baseline (775.235 us; speedup 1.0000x reference)
//
#include <hip/hip_runtime.h>
#include <hip/hip_bf16.h>
#include <stdint.h>

// ---------------------------------------------------------------------------
// MultiHeadCrossAttention, B=8 C=512 H=W=64 nh=8 d=64.
// Index algebra (t = h*64+w, f = t*512+c):
//   n = h>>3 (the HEAD), dd = (h&7)*8 + (w>>3), hh = (w&7)*8 + (c>>6), ww = c&63
// With e = hh&7, g = hh>>3: token j within slab (b,n): j = 8*dd + g.
// q broadcast over tokens -> scores rank-1:
//   scores[qq,kk] = qs[b][e*64+qq] * K2[b,n,g][e*64+kk]
//   qs = (guide@Wq^T + bq)*0.125 ; K2 = hrsum@Wk^T + 64*bk
//   hrsum[b,n,g,c'] = sum_{j==g mod 8} hid[b,c',n*512+j]
// attended[qq,dd] = sum_kk P[qq,kk] * V[e*64+kk][j(dd,g)]
//   V[c][j] = sum_c' Wv[c][c'] * hid[b][c'][n*512+j] + bv[c]
// out[b][n*64+dd][g*8+e][qq]
//
// r12 = r11 with the K-loop DE-UNROLLED (#pragma unroll 2; parity static,
// LDS base in a register). Theory: every 54-70us variant since r2 fully
// unrolled the K-loop + 2 macro tails -> ~30-50KB text vs 32KB I$/CU ->
// instruction-fetch thrash (all pipes <15%, util ~3x the static work count,
// insensitive to every data-path change). Shrink the code, change nothing
// else. If dur is unchanged, the theory is dead.
// ---------------------------------------------------------------------------

typedef __attribute__((ext_vector_type(8))) short bf16x8_t;
typedef __attribute__((ext_vector_type(4))) float f32x4_t;

__device__ __forceinline__ unsigned short f2bf(float f) {
  unsigned int u = __float_as_uint(f);
  u += 0x7FFFu + ((u >> 16) & 1u);
  return (unsigned short)(u >> 16);
}

__device__ __forceinline__ void gload16(const void* g, void* lds) {
  __builtin_amdgcn_global_load_lds(
      (const __attribute__((address_space(1))) unsigned int*)g,
      (__attribute__((address_space(3))) unsigned int*)lds, 16, 0, 0);
}

// ---------------- kernel 2: transpose hid -> XT (bf16) + hrsum (fp32) -------
// blocks [0,1024): (b,n,cb,rhalf) -> 32 c' rows x 512 j. [1024,1040): Wv cvt.
__global__ __launch_bounds__(256) void k_trans(const float* __restrict__ hid,
                                               unsigned short* __restrict__ XT,
                                               float* __restrict__ hrsum,
                                               const float* __restrict__ Wv,
                                               unsigned short* __restrict__ Wvb) {
  int bid = blockIdx.x;
  int tid = threadIdx.x;
  if (bid >= 1024) {
    int blk = bid - 1024;
#pragma unroll
    for (int i = 0; i < 16; ++i) {
      int idx = blk * 4096 + i * 256 + tid;
      float4 v = ((const float4*)Wv)[idx];
      ushort4 o;
      o.x = f2bf(v.x); o.y = f2bf(v.y); o.z = f2bf(v.z); o.w = f2bf(v.w);
      ((ushort4*)Wvb)[idx] = o;
    }
    return;
  }
  int rh = bid & 1, cb = (bid >> 1) & 7, n = (bid >> 4) & 7, b = bid >> 7;
  __shared__ float T[32][65];
  __shared__ float hsred[32][8];
  ((float*)hsred)[tid] = 0.f;

  float part[2][4];
#pragma unroll
  for (int m = 0; m < 2; ++m)
#pragma unroll
    for (int i = 0; i < 4; ++i) part[m][i] = 0.f;

  const int f4 = tid & 15;
  const int r0 = tid >> 4;
  const float* srcbase = hid + (size_t)(b * 512 + cb * 64 + rh * 32) * 4096 + n * 512;
  unsigned short* xtbase =
      XT + (size_t)(b * 8 + n) * 512 * 512 + cb * 64 + rh * 32;

  float4 va[2], vb2[2];
#pragma unroll
  for (int m = 0; m < 2; ++m)
    va[m] = *(const float4*)(srcbase + (size_t)(r0 + 16 * m) * 4096 + f4 * 4);

#define TSTEP(JC, CUR, NXT, LAST)                                              \
  do {                                                                         \
    _Pragma("unroll")                                                          \
    for (int m_ = 0; m_ < 2; ++m_) {                                           \
      int r_ = r0 + 16 * m_;                                                   \
      T[r_][f4 * 4 + 0] = CUR[m_].x;  T[r_][f4 * 4 + 1] = CUR[m_].y;           \
      T[r_][f4 * 4 + 2] = CUR[m_].z;  T[r_][f4 * 4 + 3] = CUR[m_].w;           \
      part[m_][0] += CUR[m_].x; part[m_][1] += CUR[m_].y;                      \
      part[m_][2] += CUR[m_].z; part[m_][3] += CUR[m_].w;                      \
    }                                                                          \
    if (!(LAST)) {                                                             \
      _Pragma("unroll")                                                        \
      for (int m_ = 0; m_ < 2; ++m_)                                           \
        NXT[m_] = *(const float4*)(srcbase + (size_t)(r0 + 16 * m_) * 4096 +   \
                                   ((JC) + 1) * 64 + f4 * 4);                  \
    }                                                                          \
    __syncthreads();                                                           \
    {                                                                          \
      int jl_ = tid >> 2, o_ = tid & 3;                                        \
      unsigned short t0 = f2bf(T[o_ * 8 + 0][jl_]);                            \
      unsigned short t1 = f2bf(T[o_ * 8 + 1][jl_]);                            \
      unsigned short t2 = f2bf(T[o_ * 8 + 2][jl_]);                            \
      unsigned short t3 = f2bf(T[o_ * 8 + 3][jl_]);                            \
      unsigned short t4 = f2bf(T[o_ * 8 + 4][jl_]);                            \
      unsigned short t5 = f2bf(T[o_ * 8 + 5][jl_]);                            \
      unsigned short t6 = f2bf(T[o_ * 8 + 6][jl_]);                            \
      unsigned short t7 = f2bf(T[o_ * 8 + 7][jl_]);                            \
      uint4 pk_;                                                               \
      pk_.x = (unsigned)t0 | ((unsigned)t1 << 16);                             \
      pk_.y = (unsigned)t2 | ((unsigned)t3 << 16);                             \
      pk_.z = (unsigned)t4 | ((unsigned)t5 << 16);                             \
      pk_.w = (unsigned)t6 | ((unsigned)t7 << 16);                             \
      *(uint4*)(xtbase + (size_t)((JC) * 64 + jl_) * 512 + o_ * 8) = pk_;      \
    }                                                                          \
    __syncthreads();                                                           \
  } while (0)

  TSTEP(0, va, vb2, 0);
  TSTEP(1, vb2, va, 0);
  TSTEP(2, va, vb2, 0);
  TSTEP(3, vb2, va, 0);
  TSTEP(4, va, vb2, 0);
  TSTEP(5, vb2, va, 0);
  TSTEP(6, va, vb2, 0);
  TSTEP(7, vb2, va, 1);
#undef TSTEP

  {
    int gbase = (f4 & 1) * 4;
#pragma unroll
    for (int m = 0; m < 2; ++m) {
      int r = r0 + 16 * m;
#pragma unroll
      for (int i = 0; i < 4; ++i) atomicAdd(&hsred[r][gbase + i], part[m][i]);
    }
  }
  __syncthreads();
  float* hout = hrsum + (size_t)(b * 8 + n) * 4096 + cb * 64 + rh * 32;
  {
    int g = tid >> 5, r = tid & 31;
    hout[(size_t)g * 512 + r] = hsred[r][g];
  }
}

// ---------------- kernel 3: K2 = hrsum@Wk^T + 64*bk ; qs = (guide@Wq^T+bq)/8 -
__global__ __launch_bounds__(256) void k_k2(const float* __restrict__ hrsum,
                                            const float* __restrict__ Wk,
                                            const float* __restrict__ bk,
                                            const float* __restrict__ guide,
                                            const float* __restrict__ Wq,
                                            const float* __restrict__ bq,
                                            float* __restrict__ K2,
                                            float* __restrict__ qs) {
  int bid = blockIdx.x;
  int rt = bid >> 4, ct = bid & 15;
  bool isQ = (rt == 16);
  const float* A = isQ ? guide : (hrsum + (size_t)rt * 32 * 512);
  const float* Bm = isQ ? Wq : Wk;
  int arows = isQ ? 8 : 32;
  int tid = threadIdx.x;
  __shared__ float Ah[32][36];
  __shared__ float Bh[32][36];
  int r = tid >> 3, f = tid & 7;
  int oy = (tid >> 4) * 2, ox = (tid & 15) * 2;
  float a00 = 0.f, a01 = 0.f, a10 = 0.f, a11 = 0.f;

  for (int kc = 0; kc < 16; ++kc) {
    __syncthreads();
    float4 av = (r < arows) ? *(const float4*)(A + (size_t)r * 512 + kc * 32 + f * 4)
                            : make_float4(0.f, 0.f, 0.f, 0.f);
    *(float4*)(&Ah[r][f * 4]) = av;
    float4 bv = *(const float4*)(Bm + (size_t)(ct * 32 + r) * 512 + kc * 32 + f * 4);
    *(float4*)(&Bh[r][f * 4]) = bv;
    __syncthreads();
#pragma unroll
    for (int kk = 0; kk < 32; kk += 4) {
      float4 x0 = *(float4*)(&Ah[oy][kk]);
      float4 x1 = *(float4*)(&Ah[oy + 1][kk]);
      float4 y0 = *(float4*)(&Bh[ox][kk]);
      float4 y1 = *(float4*)(&Bh[ox + 1][kk]);
      a00 += x0.x * y0.x + x0.y * y0.y + x0.z * y0.z + x0.w * y0.w;
      a01 += x0.x * y1.x + x0.y * y1.y + x0.z * y1.z + x0.w * y1.w;
      a10 += x1.x * y0.x + x1.y * y0.y + x1.z * y0.z + x1.w * y0.w;
      a11 += x1.x * y1.x + x1.y * y1.y + x1.z * y1.z + x1.w * y1.w;
    }
  }
  int c0 = ct * 32 + ox;
  if (!isQ) {
    int row0 = rt * 32 + oy;
    K2[(size_t)row0 * 512 + c0]           = a00 + 64.f * bk[c0];
    K2[(size_t)row0 * 512 + c0 + 1]       = a01 + 64.f * bk[c0 + 1];
    K2[(size_t)(row0 + 1) * 512 + c0]     = a10 + 64.f * bk[c0];
    K2[(size_t)(row0 + 1) * 512 + c0 + 1] = a11 + 64.f * bk[c0 + 1];
  } else if (oy < 8) {
    const float scale = 0.125f;
    qs[(size_t)oy * 512 + c0]           = (a00 + bq[c0]) * scale;
    qs[(size_t)oy * 512 + c0 + 1]       = (a01 + bq[c0 + 1]) * scale;
    qs[(size_t)(oy + 1) * 512 + c0]     = (a10 + bq[c0]) * scale;
    qs[(size_t)(oy + 1) * 512 + c0 + 1] = (a11 + bq[c0 + 1]) * scale;
  }
}

// ---------------- kernel 4: fused V-GEMM x2 slabs + softmax + PV -------------
// grid 256 = slab-pair(32) * g(8), XCD-grouped; 512 threads = 8 waves, w = e.
// LDS 128KB: Xa [8 kc][64 j][128B] @0, Xb @64KB. K-loop #pragma unroll 2
// (I$-size experiment). Vp overlays dead X-tiles after the loop.
__global__ __launch_bounds__(512, 2) void k_fused(
    const unsigned short* __restrict__ XT, const unsigned short* __restrict__ Wvb,
    const float* __restrict__ K2, const float* __restrict__ qs,
    const float* __restrict__ bv, float* __restrict__ out) {
  int p = blockIdx.x;
  int xcd = p & 7, idx = p >> 3;              // idx in [0,32)
  int sp = xcd * 4 + (idx & 3);               // slab pair [0,32)
  int g = idx >> 2;                           // [0,8)
  int slab0 = sp * 2, slab1 = slab0 + 1;
  int b = sp >> 2;
  int n0 = slab0 & 7, n1 = slab1 & 7;

  int tid = threadIdx.x;
  int w = tid >> 6, l = tid & 63;
  int l15 = l & 15, l4 = l >> 4, lr = l >> 3, lc = l & 7;

  __shared__ __align__(16) unsigned char smem[131072];

  const unsigned swzel = (unsigned)((lc ^ lr) << 3);  // pre-swizzled src col
  const unsigned short* xsrc0 = XT + (size_t)slab0 * 512 * 512;
  const unsigned short* xsrc1 = XT + (size_t)slab1 * 512 * 512;
  const unsigned short* wbase = Wvb + (size_t)(w * 64 + l15) * 512 + l4 * 8;
  const int brow = 8 * (w * 8 + lr) + g;

  // scalar loads first (their results feed the hoisted softmax)
  float alpha = qs[(size_t)b * 512 + w * 64 + l];               // lane = qq
  float beta0 = K2[(size_t)(slab0 * 8 + g) * 512 + w * 64 + l]; // lane = kk
  float beta1 = K2[(size_t)(slab1 * 8 + g) * 512 + w * 64 + l];
  float bvreg = bv[w * 64 + l];                                 // lane = kk

  // ---- stage both X-tiles: 16 x global_load_lds (16B) per thread ----
#pragma unroll
  for (int i = 0; i < 8; ++i)
    gload16(xsrc0 + (size_t)brow * 512 + i * 64 + swzel,
            smem + i * 8192 + w * 1024);
#pragma unroll
  for (int i = 0; i < 8; ++i)
    gload16(xsrc1 + (size_t)brow * 512 + i * 64 + swzel,
            smem + 65536 + i * 8192 + w * 1024);

  // ---- hoisted softmax scalars (overlap with the staging DMA drain) ----
  float m0, inv0, m1, inv1;
#define SOFTMAX_SCALARS(BETA, MVAR, IVAR)                                      \
  do {                                                                         \
    float bmax = (BETA), bmin = (BETA);                                        \
    _Pragma("unroll")                                                          \
    for (int o = 32; o >= 1; o >>= 1) {                                        \
      bmax = fmaxf(bmax, __shfl_xor(bmax, o));                                 \
      bmin = fminf(bmin, __shfl_xor(bmin, o));                                 \
    }                                                                          \
    MVAR = alpha >= 0.f ? alpha * bmax : alpha * bmin;                         \
    float ss = 0.f;                                                            \
    _Pragma("unroll 8")                                                        \
    for (int kk = 0; kk < 64; ++kk)                                            \
      ss += __expf(fmaf(alpha, __shfl((BETA), kk), -MVAR));                    \
    IVAR = 1.0f / ss;                                                          \
  } while (0)

  SOFTMAX_SCALARS(beta0, m0, inv0);
  SOFTMAX_SCALARS(beta1, m1, inv1);
#undef SOFTMAX_SCALARS

  f32x4_t acc0[4][4], acc1[4][4];
#pragma unroll
  for (int i = 0; i < 4; ++i)
#pragma unroll
    for (int j = 0; j < 4; ++j) {
      acc0[i][j] = (f32x4_t){0.f, 0.f, 0.f, 0.f};
      acc1[i][j] = (f32x4_t){0.f, 0.f, 0.f, 0.f};
    }

  // initial af prefetch can overlap the DMA drain too
  bf16x8_t af[2][4];
#pragma unroll
  for (int mt = 0; mt < 4; ++mt)
    af[0][mt] = *(const bf16x8_t*)(wbase + mt * 16 * 512);

  __syncthreads();   // both tiles resident for the whole K-loop

  // ---- K-loop: 16 steps, 32 MFMA/step, shared af, depth-2 prefetch.
  //      #pragma unroll 2: parity (s&1) static, code stays small (I$). ----
#pragma unroll 2
  for (int s = 0; s < 16; ++s) {
    if (s < 15) {
#pragma unroll
      for (int mt = 0; mt < 4; ++mt)
        af[(s + 1) & 1][mt] =
            *(const bf16x8_t*)(wbase + mt * 16 * 512 + (s + 1) * 32);
    }
    unsigned colx = (unsigned)((s & 1) * 64 + l4 * 16);
    unsigned char* Ba = smem + (s >> 1) * 8192;
    unsigned char* Bb = Ba + 65536;
    bf16x8_t b0[4], b1[4];
#pragma unroll
    for (int nt = 0; nt < 4; ++nt) {
      unsigned row = (unsigned)(nt * 16 + l15);
      unsigned off = row * 128 + (colx ^ ((row & 7) << 4));
      b0[nt] = *(const bf16x8_t*)(Ba + off);
      b1[nt] = *(const bf16x8_t*)(Bb + off);
    }
#pragma unroll
    for (int mt = 0; mt < 4; ++mt)
#pragma unroll
      for (int nt = 0; nt < 4; ++nt)
        acc0[mt][nt] = __builtin_amdgcn_mfma_f32_16x16x32_bf16(
            af[s & 1][mt], b0[nt], acc0[mt][nt], 0, 0, 0);
#pragma unroll
    for (int mt = 0; mt < 4; ++mt)
#pragma unroll
      for (int nt = 0; nt < 4; ++nt)
        acc1[mt][nt] = __builtin_amdgcn_mfma_f32_16x16x32_bf16(
            af[s & 1][mt], b1[nt], acc1[mt][nt], 0, 0, 0);
  }

  __syncthreads();   // all waves done reading both X-tiles; safe to overlay

  // ---- per-slab: spill V -> wave-private LDS, then PV (D[qq][dd]) + store ---
  // GEMM acc[mt][nt] reg r: kk = mt*16 + l4*4 + r, dd = nt*16 + l15.
  // PV: A = pa (P, rows qq), B = va (V^T, rows dd) -> D[m=qq][n=dd];
  // acc2[mt2][nt2] reg r: qq = mt2*16 + l4*4 + r, dd = nt2*16 + l15
  // -> float4 store along qq (contiguous last axis).
#define SLAB_TAIL(ACC, VPOFF, BETA, MM, INV, NN)                               \
  do {                                                                         \
    unsigned char* Vp = smem + (VPOFF) + w * 8192;                             \
    _Pragma("unroll")                                                          \
    for (int mt = 0; mt < 4; ++mt) {                                           \
      float bq0 = __shfl(bvreg, mt * 16 + l4 * 4 + 0);                         \
      float bq1 = __shfl(bvreg, mt * 16 + l4 * 4 + 1);                         \
      float bq2 = __shfl(bvreg, mt * 16 + l4 * 4 + 2);                         \
      float bq3 = __shfl(bvreg, mt * 16 + l4 * 4 + 3);                         \
      _Pragma("unroll")                                                        \
      for (int nt = 0; nt < 4; ++nt) {                                         \
        unsigned dd = (unsigned)(nt * 16 + l15);                               \
        uint2 pk;                                                              \
        pk.x = (unsigned)f2bf(ACC[mt][nt][0] + bq0) |                          \
               ((unsigned)f2bf(ACC[mt][nt][1] + bq1) << 16);                   \
        pk.y = (unsigned)f2bf(ACC[mt][nt][2] + bq2) |                          \
               ((unsigned)f2bf(ACC[mt][nt][3] + bq3) << 16);                   \
        *(uint2*)(Vp + dd * 128 +                                              \
                  ((unsigned)(mt * 32 + l4 * 8) ^ ((dd & 7) << 4))) = pk;      \
      }                                                                        \
    }                                                                          \
    f32x4_t acc2[4][4];                                                        \
    _Pragma("unroll")                                                          \
    for (int i = 0; i < 4; ++i)                                                \
      _Pragma("unroll")                                                        \
      for (int j = 0; j < 4; ++j) acc2[i][j] = (f32x4_t){0.f, 0.f, 0.f, 0.f};  \
    _Pragma("unroll")                                                          \
    for (int ks = 0; ks < 2; ++ks) {                                           \
      bf16x8_t va[4];                                                          \
      _Pragma("unroll")                                                        \
      for (int nt = 0; nt < 4; ++nt) {                                         \
        unsigned dd = (unsigned)(nt * 16 + l15);                               \
        va[nt] = *(const bf16x8_t*)(Vp + dd * 128 +                            \
                  ((unsigned)(ks * 64 + l4 * 16) ^ ((dd & 7) << 4)));          \
      }                                                                        \
      float bb[8];                                                             \
      _Pragma("unroll")                                                        \
      for (int i = 0; i < 8; ++i)                                              \
        bb[i] = __shfl((BETA), ks * 32 + l4 * 8 + i);                          \
      bf16x8_t pa[4];                                                          \
      _Pragma("unroll")                                                        \
      for (int mt = 0; mt < 4; ++mt) {                                         \
        int qq = mt * 16 + l15;                                                \
        float aq = __shfl(alpha, qq);                                          \
        float mq = __shfl((MM), qq);                                           \
        float iq = __shfl((INV), qq);                                          \
        bf16x8_t pp;                                                           \
        _Pragma("unroll")                                                      \
        for (int i = 0; i < 8; ++i)                                            \
          pp[i] = (short)f2bf(__expf(fmaf(aq, bb[i], -mq)) * iq);              \
        pa[mt] = pp;                                                           \
      }                                                                        \
      _Pragma("unroll")                                                        \
      for (int mt = 0; mt < 4; ++mt)                                           \
        _Pragma("unroll")                                                      \
        for (int nt = 0; nt < 4; ++nt)                                         \
          acc2[mt][nt] = __builtin_amdgcn_mfma_f32_16x16x32_bf16(              \
              pa[mt], va[nt], acc2[mt][nt], 0, 0, 0);                          \
    }                                                                          \
    _Pragma("unroll")                                                          \
    for (int nt = 0; nt < 4; ++nt) {                                           \
      int dd = nt * 16 + l15;                                                  \
      size_t base =                                                            \
          (((size_t)(b * 512 + (NN) * 64 + dd)) * 64 + (g * 8 + w)) * 64;      \
      _Pragma("unroll")                                                        \
      for (int mt = 0; mt < 4; ++mt) {                                         \
        float4 v = make_float4(acc2[mt][nt][0], acc2[mt][nt][1],               \
                               acc2[mt][nt][2], acc2[mt][nt][3]);              \
        *(float4*)(out + base + mt * 16 + l4 * 4) = v;                         \
      }                                                                        \
    }                                                                          \
  } while (0)

  SLAB_TAIL(acc0, 0, beta0, m0, inv0, n0);
  SLAB_TAIL(acc1, 65536, beta1, m1, inv1, n1);
#undef SLAB_TAIL
}

// ---------------------------------------------------------------------------
extern "C" void kernel_launch(void* const* d_in, const int* in_sizes, int n_in,
                              void* d_out, int out_size, void* d_ws, size_t ws_size,
                              hipStream_t stream) {
  const float* guide = (const float*)d_in[0];
  const float* hid   = (const float*)d_in[1];
  const float* Wq    = (const float*)d_in[2];
  const float* bq    = (const float*)d_in[3];
  const float* Wk    = (const float*)d_in[4];
  const float* bk    = (const float*)d_in[5];
  const float* Wv    = (const float*)d_in[6];
  const float* bv    = (const float*)d_in[7];
  float* out = (float*)d_out;

  char* ws = (char*)d_ws;
  unsigned short* XT  = (unsigned short*)(ws);             // 33,554,432 B
  unsigned short* Wvb = (unsigned short*)(ws + 33554432);  //    524,288 B
  float* hrsum        = (float*)(ws + 34078720);           //  1,048,576 B
  float* K2           = (float*)(ws + 35127296);           //  1,048,576 B
  float* qs           = (float*)(ws + 36175872);           //     16,384 B

  k_trans<<<1040, 256, 0, stream>>>(hid, XT, hrsum, Wv, Wvb);
  k_k2<<<272, 256, 0, stream>>>(hrsum, Wk, bk, guide, Wq, bq, K2, qs);
  k_fused<<<256, 512, 0, stream>>>(XT, Wvb, K2, qs, bv, out);
}

// Round 13
// 117.706 us; speedup vs baseline: 6.5862x; 6.5862x over previous
//
#include <hip/hip_runtime.h>
#include <hip/hip_bf16.h>
#include <stdint.h>

// ---------------------------------------------------------------------------
// MultiHeadCrossAttention, B=8 C=512 H=W=64 nh=8 d=64.
// Index algebra (t = h*64+w, f = t*512+c):
//   n = h>>3 (the HEAD), dd = (h&7)*8 + (w>>3), hh = (w&7)*8 + (c>>6), ww = c&63
// With e = hh&7, g = hh>>3: token j within slab (b,n): j = 8*dd + g.
// q broadcast over tokens -> scores rank-1:
//   scores[qq,kk] = qs[b][e*64+qq] * K2[b,n,g][e*64+kk]
//   qs = (guide@Wq^T + bq)*0.125 ; K2 = hrsum@Wk^T + 64*bk
//   hrsum[b,n,g,c'] = sum_{j==g mod 8} hid[b,c',n*512+j]
// attended[qq,dd] = sum_kk P[qq,kk] * V[e*64+kk][j(dd,g)]
//   V[c][j] = sum_c' Wv[c][c'] * hid[b][c'][n*512+j] + bv[c]
// out[b][n*64+dd][g*8+e][qq]
//
// r13: ZERO-COUPLING WAVES. r2-r11 all kept block-lockstep (barriers, DMA
// drains, LDS staging) and all pinned at 54-70us with every pipe <15% —
// latency exposure that 2 waves/SIMD can't hide, propagated by barriers.
// New k_attn: one independent 64-thread wave per (slab,g,e). B-fragments
// loaded DIRECTLY from L2-resident XT (16B/lane = fragment layout), af from
// L2-resident Wvb, no barriers, wave-private 8KB Vp spill (r10-verified),
// swapped PV + float4 stores (r11-verified). <=128 VGPR -> whole 4096-wave
// grid co-resident at 16 waves/CU: hide latency with TLP, not scheduling.
// ---------------------------------------------------------------------------

typedef __attribute__((ext_vector_type(8))) short bf16x8_t;
typedef __attribute__((ext_vector_type(4))) float f32x4_t;

__device__ __forceinline__ unsigned short f2bf(float f) {
  unsigned int u = __float_as_uint(f);
  u += 0x7FFFu + ((u >> 16) & 1u);
  return (unsigned short)(u >> 16);
}

// ---------------- kernel 2: transpose hid -> XT (bf16) + hrsum (fp32) -------
// blocks [0,1024): (b,n,cb,rhalf) -> 32 c' rows x 512 j. [1024,1040): Wv cvt.
__global__ __launch_bounds__(256) void k_trans(const float* __restrict__ hid,
                                               unsigned short* __restrict__ XT,
                                               float* __restrict__ hrsum,
                                               const float* __restrict__ Wv,
                                               unsigned short* __restrict__ Wvb) {
  int bid = blockIdx.x;
  int tid = threadIdx.x;
  if (bid >= 1024) {
    int blk = bid - 1024;
#pragma unroll
    for (int i = 0; i < 16; ++i) {
      int idx = blk * 4096 + i * 256 + tid;
      float4 v = ((const float4*)Wv)[idx];
      ushort4 o;
      o.x = f2bf(v.x); o.y = f2bf(v.y); o.z = f2bf(v.z); o.w = f2bf(v.w);
      ((ushort4*)Wvb)[idx] = o;
    }
    return;
  }
  int rh = bid & 1, cb = (bid >> 1) & 7, n = (bid >> 4) & 7, b = bid >> 7;
  __shared__ float T[32][65];
  __shared__ float hsred[32][8];
  ((float*)hsred)[tid] = 0.f;

  float part[2][4];
#pragma unroll
  for (int m = 0; m < 2; ++m)
#pragma unroll
    for (int i = 0; i < 4; ++i) part[m][i] = 0.f;

  const int f4 = tid & 15;
  const int r0 = tid >> 4;
  const float* srcbase = hid + (size_t)(b * 512 + cb * 64 + rh * 32) * 4096 + n * 512;
  unsigned short* xtbase =
      XT + (size_t)(b * 8 + n) * 512 * 512 + cb * 64 + rh * 32;

  float4 va[2], vb2[2];
#pragma unroll
  for (int m = 0; m < 2; ++m)
    va[m] = *(const float4*)(srcbase + (size_t)(r0 + 16 * m) * 4096 + f4 * 4);

#define TSTEP(JC, CUR, NXT, LAST)                                              \
  do {                                                                         \
    _Pragma("unroll")                                                          \
    for (int m_ = 0; m_ < 2; ++m_) {                                           \
      int r_ = r0 + 16 * m_;                                                   \
      T[r_][f4 * 4 + 0] = CUR[m_].x;  T[r_][f4 * 4 + 1] = CUR[m_].y;           \
      T[r_][f4 * 4 + 2] = CUR[m_].z;  T[r_][f4 * 4 + 3] = CUR[m_].w;           \
      part[m_][0] += CUR[m_].x; part[m_][1] += CUR[m_].y;                      \
      part[m_][2] += CUR[m_].z; part[m_][3] += CUR[m_].w;                      \
    }                                                                          \
    if (!(LAST)) {                                                             \
      _Pragma("unroll")                                                        \
      for (int m_ = 0; m_ < 2; ++m_)                                           \
        NXT[m_] = *(const float4*)(srcbase + (size_t)(r0 + 16 * m_) * 4096 +   \
                                   ((JC) + 1) * 64 + f4 * 4);                  \
    }                                                                          \
    __syncthreads();                                                           \
    {                                                                          \
      int jl_ = tid >> 2, o_ = tid & 3;                                        \
      unsigned short t0 = f2bf(T[o_ * 8 + 0][jl_]);                            \
      unsigned short t1 = f2bf(T[o_ * 8 + 1][jl_]);                            \
      unsigned short t2 = f2bf(T[o_ * 8 + 2][jl_]);                            \
      unsigned short t3 = f2bf(T[o_ * 8 + 3][jl_]);                            \
      unsigned short t4 = f2bf(T[o_ * 8 + 4][jl_]);                            \
      unsigned short t5 = f2bf(T[o_ * 8 + 5][jl_]);                            \
      unsigned short t6 = f2bf(T[o_ * 8 + 6][jl_]);                            \
      unsigned short t7 = f2bf(T[o_ * 8 + 7][jl_]);                            \
      uint4 pk_;                                                               \
      pk_.x = (unsigned)t0 | ((unsigned)t1 << 16);                             \
      pk_.y = (unsigned)t2 | ((unsigned)t3 << 16);                             \
      pk_.z = (unsigned)t4 | ((unsigned)t5 << 16);                             \
      pk_.w = (unsigned)t6 | ((unsigned)t7 << 16);                             \
      *(uint4*)(xtbase + (size_t)((JC) * 64 + jl_) * 512 + o_ * 8) = pk_;      \
    }                                                                          \
    __syncthreads();                                                           \
  } while (0)

  TSTEP(0, va, vb2, 0);
  TSTEP(1, vb2, va, 0);
  TSTEP(2, va, vb2, 0);
  TSTEP(3, vb2, va, 0);
  TSTEP(4, va, vb2, 0);
  TSTEP(5, vb2, va, 0);
  TSTEP(6, va, vb2, 0);
  TSTEP(7, vb2, va, 1);
#undef TSTEP

  {
    int gbase = (f4 & 1) * 4;
#pragma unroll
    for (int m = 0; m < 2; ++m) {
      int r = r0 + 16 * m;
#pragma unroll
      for (int i = 0; i < 4; ++i) atomicAdd(&hsred[r][gbase + i], part[m][i]);
    }
  }
  __syncthreads();
  float* hout = hrsum + (size_t)(b * 8 + n) * 4096 + cb * 64 + rh * 32;
  {
    int g = tid >> 5, r = tid & 31;
    hout[(size_t)g * 512 + r] = hsred[r][g];
  }
}

// ---------------- kernel 3: K2 = hrsum@Wk^T + 64*bk ; qs = (guide@Wq^T+bq)/8 -
__global__ __launch_bounds__(256) void k_k2(const float* __restrict__ hrsum,
                                            const float* __restrict__ Wk,
                                            const float* __restrict__ bk,
                                            const float* __restrict__ guide,
                                            const float* __restrict__ Wq,
                                            const float* __restrict__ bq,
                                            float* __restrict__ K2,
                                            float* __restrict__ qs) {
  int bid = blockIdx.x;
  int rt = bid >> 4, ct = bid & 15;
  bool isQ = (rt == 16);
  const float* A = isQ ? guide : (hrsum + (size_t)rt * 32 * 512);
  const float* Bm = isQ ? Wq : Wk;
  int arows = isQ ? 8 : 32;
  int tid = threadIdx.x;
  __shared__ float Ah[32][36];
  __shared__ float Bh[32][36];
  int r = tid >> 3, f = tid & 7;
  int oy = (tid >> 4) * 2, ox = (tid & 15) * 2;
  float a00 = 0.f, a01 = 0.f, a10 = 0.f, a11 = 0.f;

  for (int kc = 0; kc < 16; ++kc) {
    __syncthreads();
    float4 av = (r < arows) ? *(const float4*)(A + (size_t)r * 512 + kc * 32 + f * 4)
                            : make_float4(0.f, 0.f, 0.f, 0.f);
    *(float4*)(&Ah[r][f * 4]) = av;
    float4 bv = *(const float4*)(Bm + (size_t)(ct * 32 + r) * 512 + kc * 32 + f * 4);
    *(float4*)(&Bh[r][f * 4]) = bv;
    __syncthreads();
#pragma unroll
    for (int kk = 0; kk < 32; kk += 4) {
      float4 x0 = *(float4*)(&Ah[oy][kk]);
      float4 x1 = *(float4*)(&Ah[oy + 1][kk]);
      float4 y0 = *(float4*)(&Bh[ox][kk]);
      float4 y1 = *(float4*)(&Bh[ox + 1][kk]);
      a00 += x0.x * y0.x + x0.y * y0.y + x0.z * y0.z + x0.w * y0.w;
      a01 += x0.x * y1.x + x0.y * y1.y + x0.z * y1.z + x0.w * y1.w;
      a10 += x1.x * y0.x + x1.y * y0.y + x1.z * y0.z + x1.w * y0.w;
      a11 += x1.x * y1.x + x1.y * y1.y + x1.z * y1.z + x1.w * y1.w;
    }
  }
  int c0 = ct * 32 + ox;
  if (!isQ) {
    int row0 = rt * 32 + oy;
    K2[(size_t)row0 * 512 + c0]           = a00 + 64.f * bk[c0];
    K2[(size_t)row0 * 512 + c0 + 1]       = a01 + 64.f * bk[c0 + 1];
    K2[(size_t)(row0 + 1) * 512 + c0]     = a10 + 64.f * bk[c0];
    K2[(size_t)(row0 + 1) * 512 + c0 + 1] = a11 + 64.f * bk[c0 + 1];
  } else if (oy < 8) {
    const float scale = 0.125f;
    qs[(size_t)oy * 512 + c0]           = (a00 + bq[c0]) * scale;
    qs[(size_t)oy * 512 + c0 + 1]       = (a01 + bq[c0 + 1]) * scale;
    qs[(size_t)(oy + 1) * 512 + c0]     = (a10 + bq[c0]) * scale;
    qs[(size_t)(oy + 1) * 512 + c0 + 1] = (a11 + bq[c0 + 1]) * scale;
  }
}

// ---------------- kernel 4: independent-wave V-GEMM + softmax + PV ----------
// grid 4096 = (slab,g,e), XCD-swizzled (8 full slabs per XCD); 64 threads =
// ONE wave. No barriers, no staging: B-fragments straight from L2-resident
// XT, A-fragments from L2-resident Wvb. 8KB wave-private Vp for the V spill.
__global__ __launch_bounds__(64, 4) void k_attn(
    const unsigned short* __restrict__ XT, const unsigned short* __restrict__ Wvb,
    const float* __restrict__ K2, const float* __restrict__ qs,
    const float* __restrict__ bv, float* __restrict__ out) {
  int p = blockIdx.x;
  int xcd = p & 7, i = p >> 3;          // i in [0,512)
  int slab = xcd * 8 + (i >> 6);        // 8 complete slabs per XCD
  int rem = i & 63;
  int g = rem >> 3, e = rem & 7;
  int b = slab >> 3, n = slab & 7;

  int l = threadIdx.x;
  int l15 = l & 15, l4 = l >> 4;

  __shared__ __align__(16) unsigned char Vp[8192];

  // B-fragment base: row j = 8*dd + g, dd = nt*16 + l15, col = s*32 + l4*8.
  const unsigned short* xbase =
      XT + (size_t)slab * 262144 + (size_t)l15 * 4096 + g * 512 + l4 * 8;
  // A-fragment base: row e*64 + mt*16 + l15, col = s*32 + l4*8.
  const unsigned short* wbase = Wvb + (size_t)(e * 64 + l15) * 512 + l4 * 8;

  float alpha = qs[(size_t)b * 512 + e * 64 + l];              // lane = qq
  float beta  = K2[(size_t)(slab * 8 + g) * 512 + e * 64 + l]; // lane = kk
  float bvreg = bv[e * 64 + l];                                // lane = kk

  // ---- softmax scalars (rank-1; wave-local) ----
  float bmax = beta, bmin = beta;
#pragma unroll
  for (int o = 32; o >= 1; o >>= 1) {
    bmax = fmaxf(bmax, __shfl_xor(bmax, o));
    bmin = fminf(bmin, __shfl_xor(bmin, o));
  }
  float m = alpha >= 0.f ? alpha * bmax : alpha * bmin;
  float ssum = 0.f;
#pragma unroll 8
  for (int kk = 0; kk < 64; ++kk)
    ssum += __expf(fmaf(alpha, __shfl(beta, kk), -m));
  float inv = 1.0f / ssum;

  // ---- V-GEMM: 16 K32-steps, fragments straight from global (L2) ----
  f32x4_t acc[4][4];
#pragma unroll
  for (int mi = 0; mi < 4; ++mi)
#pragma unroll
    for (int j = 0; j < 4; ++j) acc[mi][j] = (f32x4_t){0.f, 0.f, 0.f, 0.f};

#pragma unroll
  for (int s = 0; s < 16; ++s) {
    bf16x8_t af[4], bf[4];
#pragma unroll
    for (int mt = 0; mt < 4; ++mt)
      af[mt] = *(const bf16x8_t*)(wbase + mt * 16 * 512 + s * 32);
#pragma unroll
    for (int nt = 0; nt < 4; ++nt)
      bf[nt] = *(const bf16x8_t*)(xbase + (size_t)nt * 65536 + s * 32);
#pragma unroll
    for (int mt = 0; mt < 4; ++mt)
#pragma unroll
      for (int nt = 0; nt < 4; ++nt)
        acc[mt][nt] = __builtin_amdgcn_mfma_f32_16x16x32_bf16(
            af[mt], bf[nt], acc[mt][nt], 0, 0, 0);
  }

  // ---- spill V + bias -> Vp[dd][kk] bf16 (XOR-swizzled; wave-private) ----
  // acc[mt][nt] reg r: kk = mt*16 + l4*4 + r, dd = nt*16 + l15.
#pragma unroll
  for (int mt = 0; mt < 4; ++mt) {
    float bq0 = __shfl(bvreg, mt * 16 + l4 * 4 + 0);
    float bq1 = __shfl(bvreg, mt * 16 + l4 * 4 + 1);
    float bq2 = __shfl(bvreg, mt * 16 + l4 * 4 + 2);
    float bq3 = __shfl(bvreg, mt * 16 + l4 * 4 + 3);
#pragma unroll
    for (int nt = 0; nt < 4; ++nt) {
      unsigned dd = (unsigned)(nt * 16 + l15);
      uint2 pk;
      pk.x = (unsigned)f2bf(acc[mt][nt][0] + bq0) |
             ((unsigned)f2bf(acc[mt][nt][1] + bq1) << 16);
      pk.y = (unsigned)f2bf(acc[mt][nt][2] + bq2) |
             ((unsigned)f2bf(acc[mt][nt][3] + bq3) << 16);
      *(uint2*)(Vp + dd * 128 +
                ((unsigned)(mt * 32 + l4 * 8) ^ ((dd & 7) << 4))) = pk;
    }
  }

  // ---- PV: A = pa (P rows qq), B = va (V^T rows dd) -> D[qq][dd] ----
  f32x4_t acc2[4][4];
#pragma unroll
  for (int mi = 0; mi < 4; ++mi)
#pragma unroll
    for (int j = 0; j < 4; ++j) acc2[mi][j] = (f32x4_t){0.f, 0.f, 0.f, 0.f};

#pragma unroll
  for (int ks = 0; ks < 2; ++ks) {
    bf16x8_t va[4];
#pragma unroll
    for (int nt = 0; nt < 4; ++nt) {
      unsigned dd = (unsigned)(nt * 16 + l15);
      va[nt] = *(const bf16x8_t*)(Vp + dd * 128 +
                ((unsigned)(ks * 64 + l4 * 16) ^ ((dd & 7) << 4)));
    }
    float bb[8];
#pragma unroll
    for (int i2 = 0; i2 < 8; ++i2) bb[i2] = __shfl(beta, ks * 32 + l4 * 8 + i2);
    bf16x8_t pa[4];
#pragma unroll
    for (int mt = 0; mt < 4; ++mt) {
      int qq = mt * 16 + l15;
      float aq = __shfl(alpha, qq);
      float mq = __shfl(m, qq);
      float iq = __shfl(inv, qq);
      bf16x8_t pp;
#pragma unroll
      for (int i2 = 0; i2 < 8; ++i2)
        pp[i2] = (short)f2bf(__expf(fmaf(aq, bb[i2], -mq)) * iq);
      pa[mt] = pp;
    }
#pragma unroll
    for (int mt = 0; mt < 4; ++mt)
#pragma unroll
      for (int nt = 0; nt < 4; ++nt)
        acc2[mt][nt] = __builtin_amdgcn_mfma_f32_16x16x32_bf16(
            pa[mt], va[nt], acc2[mt][nt], 0, 0, 0);
  }

  // ---- float4 stores: acc2[mt][nt] reg r: qq = mt*16+l4*4+r, dd = nt*16+l15
#pragma unroll
  for (int nt = 0; nt < 4; ++nt) {
    int dd = nt * 16 + l15;
    size_t base = (((size_t)(b * 512 + n * 64 + dd)) * 64 + (g * 8 + e)) * 64;
#pragma unroll
    for (int mt = 0; mt < 4; ++mt) {
      float4 v = make_float4(acc2[mt][nt][0], acc2[mt][nt][1],
                             acc2[mt][nt][2], acc2[mt][nt][3]);
      *(float4*)(out + base + mt * 16 + l4 * 4) = v;
    }
  }
}

// ---------------------------------------------------------------------------
extern "C" void kernel_launch(void* const* d_in, const int* in_sizes, int n_in,
                              void* d_out, int out_size, void* d_ws, size_t ws_size,
                              hipStream_t stream) {
  const float* guide = (const float*)d_in[0];
  const float* hid   = (const float*)d_in[1];
  const float* Wq    = (const float*)d_in[2];
  const float* bq    = (const float*)d_in[3];
  const float* Wk    = (const float*)d_in[4];
  const float* bk    = (const float*)d_in[5];
  const float* Wv    = (const float*)d_in[6];
  const float* bv    = (const float*)d_in[7];
  float* out = (float*)d_out;

  char* ws = (char*)d_ws;
  unsigned short* XT  = (unsigned short*)(ws);             // 33,554,432 B
  unsigned short* Wvb = (unsigned short*)(ws + 33554432);  //    524,288 B
  float* hrsum        = (float*)(ws + 34078720);           //  1,048,576 B
  float* K2           = (float*)(ws + 35127296);           //  1,048,576 B
  float* qs           = (float*)(ws + 36175872);           //     16,384 B

  k_trans<<<1040, 256, 0, stream>>>(hid, XT, hrsum, Wv, Wvb);
  k_k2<<<272, 256, 0, stream>>>(hrsum, Wk, bk, guide, Wq, bq, K2, qs);
  k_attn<<<4096, 64, 0, stream>>>(XT, Wvb, K2, qs, bv, out);
}

// Round 14
// 84.766 us; speedup vs baseline: 9.1456x; 1.3886x over previous
//
#include <hip/hip_runtime.h>
#include <hip/hip_bf16.h>
#include <stdint.h>

// ---------------------------------------------------------------------------
// MultiHeadCrossAttention, B=8 C=512 H=W=64 nh=8 d=64.
// Index algebra (t = h*64+w, f = t*512+c):
//   n = h>>3 (the HEAD), dd = (h&7)*8 + (w>>3), hh = (w&7)*8 + (c>>6), ww = c&63
// With e = hh&7, g = hh>>3: token j within slab (b,n): j = 8*dd + g.
// q broadcast over tokens -> scores rank-1:
//   scores[qq,kk] = qs[b][e*64+qq] * K2[b,n,g][e*64+kk]
//   qs = (guide@Wq^T + bq)*0.125 ; K2 = hrsum@Wk^T + 64*bk
//   hrsum[b,n,g,c'] = sum_{j==g mod 8} hid[b,c',n*512+j]
// attended[qq,dd] = sum_kk P[qq,kk] * V[e*64+kk][j(dd,g)]
//   V[c][j] = sum_c' Wv[c][c'] * hid[b][c'][n*512+j] + bv[c]
// out[b][n*64+dd][g*8+e][qq]
//
// r14 = r10 (best total, 84.2us) + G-BLOCKED XT: XTg[slab][g][dd 64][c' 512]
// (same bytes, permuted rows). k_fused's 128KB staging becomes two contiguous
// 64KB regions (was 64 rows strided 8KB over 1MB) -> better DRAM/L2 locality
// on the latency-exposed staging drain. LDS content identical (rows were
// already dd-ordered); all downstream math untouched.
// ---------------------------------------------------------------------------

typedef __attribute__((ext_vector_type(8))) short bf16x8_t;
typedef __attribute__((ext_vector_type(4))) float f32x4_t;

__device__ __forceinline__ unsigned short f2bf(float f) {
  unsigned int u = __float_as_uint(f);
  u += 0x7FFFu + ((u >> 16) & 1u);
  return (unsigned short)(u >> 16);
}

__device__ __forceinline__ void gload16(const void* g, void* lds) {
  __builtin_amdgcn_global_load_lds(
      (const __attribute__((address_space(1))) unsigned int*)g,
      (__attribute__((address_space(3))) unsigned int*)lds, 16, 0, 0);
}

// ---------------- kernel 2: transpose hid -> XTg (bf16) + hrsum (fp32) ------
// blocks [0,1024): (b,n,cb,rhalf) -> 32 c' rows x 512 j. [1024,1040): Wv cvt.
__global__ __launch_bounds__(256) void k_trans(const float* __restrict__ hid,
                                               unsigned short* __restrict__ XT,
                                               float* __restrict__ hrsum,
                                               const float* __restrict__ Wv,
                                               unsigned short* __restrict__ Wvb) {
  int bid = blockIdx.x;
  int tid = threadIdx.x;
  if (bid >= 1024) {
    int blk = bid - 1024;
#pragma unroll
    for (int i = 0; i < 16; ++i) {
      int idx = blk * 4096 + i * 256 + tid;
      float4 v = ((const float4*)Wv)[idx];
      ushort4 o;
      o.x = f2bf(v.x); o.y = f2bf(v.y); o.z = f2bf(v.z); o.w = f2bf(v.w);
      ((ushort4*)Wvb)[idx] = o;
    }
    return;
  }
  int rh = bid & 1, cb = (bid >> 1) & 7, n = (bid >> 4) & 7, b = bid >> 7;
  __shared__ float T[32][65];
  __shared__ float hsred[32][8];
  ((float*)hsred)[tid] = 0.f;

  float part[2][4];
#pragma unroll
  for (int m = 0; m < 2; ++m)
#pragma unroll
    for (int i = 0; i < 4; ++i) part[m][i] = 0.f;

  const int f4 = tid & 15;
  const int r0 = tid >> 4;
  const float* srcbase = hid + (size_t)(b * 512 + cb * 64 + rh * 32) * 4096 + n * 512;
  // g-blocked XT: XTg[slab][g][dd][c']; this block owns c' = cb*64+rh*32+[0,32)
  unsigned short* xtbase =
      XT + (size_t)(b * 8 + n) * 262144 + cb * 64 + rh * 32;

  float4 va[2], vb2[2];
#pragma unroll
  for (int m = 0; m < 2; ++m)
    va[m] = *(const float4*)(srcbase + (size_t)(r0 + 16 * m) * 4096 + f4 * 4);

#define TSTEP(JC, CUR, NXT, LAST)                                              \
  do {                                                                         \
    _Pragma("unroll")                                                          \
    for (int m_ = 0; m_ < 2; ++m_) {                                           \
      int r_ = r0 + 16 * m_;                                                   \
      T[r_][f4 * 4 + 0] = CUR[m_].x;  T[r_][f4 * 4 + 1] = CUR[m_].y;           \
      T[r_][f4 * 4 + 2] = CUR[m_].z;  T[r_][f4 * 4 + 3] = CUR[m_].w;           \
      part[m_][0] += CUR[m_].x; part[m_][1] += CUR[m_].y;                      \
      part[m_][2] += CUR[m_].z; part[m_][3] += CUR[m_].w;                      \
    }                                                                          \
    if (!(LAST)) {                                                             \
      _Pragma("unroll")                                                        \
      for (int m_ = 0; m_ < 2; ++m_)                                           \
        NXT[m_] = *(const float4*)(srcbase + (size_t)(r0 + 16 * m_) * 4096 +   \
                                   ((JC) + 1) * 64 + f4 * 4);                  \
    }                                                                          \
    __syncthreads();                                                           \
    {                                                                          \
      int jl_ = tid >> 2, o_ = tid & 3;                                        \
      unsigned short t0 = f2bf(T[o_ * 8 + 0][jl_]);                            \
      unsigned short t1 = f2bf(T[o_ * 8 + 1][jl_]);                            \
      unsigned short t2 = f2bf(T[o_ * 8 + 2][jl_]);                            \
      unsigned short t3 = f2bf(T[o_ * 8 + 3][jl_]);                            \
      unsigned short t4 = f2bf(T[o_ * 8 + 4][jl_]);                            \
      unsigned short t5 = f2bf(T[o_ * 8 + 5][jl_]);                            \
      unsigned short t6 = f2bf(T[o_ * 8 + 6][jl_]);                            \
      unsigned short t7 = f2bf(T[o_ * 8 + 7][jl_]);                            \
      uint4 pk_;                                                               \
      pk_.x = (unsigned)t0 | ((unsigned)t1 << 16);                             \
      pk_.y = (unsigned)t2 | ((unsigned)t3 << 16);                             \
      pk_.z = (unsigned)t4 | ((unsigned)t5 << 16);                             \
      pk_.w = (unsigned)t6 | ((unsigned)t7 << 16);                             \
      int g_ = jl_ & 7;                                                        \
      int dd_ = (JC) * 8 + (jl_ >> 3);                                         \
      *(uint4*)(xtbase + (size_t)g_ * 32768 + (size_t)dd_ * 512 + o_ * 8) =    \
          pk_;                                                                 \
    }                                                                          \
    __syncthreads();                                                           \
  } while (0)

  TSTEP(0, va, vb2, 0);
  TSTEP(1, vb2, va, 0);
  TSTEP(2, va, vb2, 0);
  TSTEP(3, vb2, va, 0);
  TSTEP(4, va, vb2, 0);
  TSTEP(5, vb2, va, 0);
  TSTEP(6, va, vb2, 0);
  TSTEP(7, vb2, va, 1);
#undef TSTEP

  {
    int gbase = (f4 & 1) * 4;
#pragma unroll
    for (int m = 0; m < 2; ++m) {
      int r = r0 + 16 * m;
#pragma unroll
      for (int i = 0; i < 4; ++i) atomicAdd(&hsred[r][gbase + i], part[m][i]);
    }
  }
  __syncthreads();
  float* hout = hrsum + (size_t)(b * 8 + n) * 4096 + cb * 64 + rh * 32;
  {
    int g = tid >> 5, r = tid & 31;
    hout[(size_t)g * 512 + r] = hsred[r][g];
  }
}

// ---------------- kernel 3: K2 = hrsum@Wk^T + 64*bk ; qs = (guide@Wq^T+bq)/8 -
__global__ __launch_bounds__(256) void k_k2(const float* __restrict__ hrsum,
                                            const float* __restrict__ Wk,
                                            const float* __restrict__ bk,
                                            const float* __restrict__ guide,
                                            const float* __restrict__ Wq,
                                            const float* __restrict__ bq,
                                            float* __restrict__ K2,
                                            float* __restrict__ qs) {
  int bid = blockIdx.x;
  int rt = bid >> 4, ct = bid & 15;
  bool isQ = (rt == 16);
  const float* A = isQ ? guide : (hrsum + (size_t)rt * 32 * 512);
  const float* Bm = isQ ? Wq : Wk;
  int arows = isQ ? 8 : 32;
  int tid = threadIdx.x;
  __shared__ float Ah[32][36];
  __shared__ float Bh[32][36];
  int r = tid >> 3, f = tid & 7;
  int oy = (tid >> 4) * 2, ox = (tid & 15) * 2;
  float a00 = 0.f, a01 = 0.f, a10 = 0.f, a11 = 0.f;

  for (int kc = 0; kc < 16; ++kc) {
    __syncthreads();
    float4 av = (r < arows) ? *(const float4*)(A + (size_t)r * 512 + kc * 32 + f * 4)
                            : make_float4(0.f, 0.f, 0.f, 0.f);
    *(float4*)(&Ah[r][f * 4]) = av;
    float4 bv = *(const float4*)(Bm + (size_t)(ct * 32 + r) * 512 + kc * 32 + f * 4);
    *(float4*)(&Bh[r][f * 4]) = bv;
    __syncthreads();
#pragma unroll
    for (int kk = 0; kk < 32; kk += 4) {
      float4 x0 = *(float4*)(&Ah[oy][kk]);
      float4 x1 = *(float4*)(&Ah[oy + 1][kk]);
      float4 y0 = *(float4*)(&Bh[ox][kk]);
      float4 y1 = *(float4*)(&Bh[ox + 1][kk]);
      a00 += x0.x * y0.x + x0.y * y0.y + x0.z * y0.z + x0.w * y0.w;
      a01 += x0.x * y1.x + x0.y * y1.y + x0.z * y1.z + x0.w * y1.w;
      a10 += x1.x * y0.x + x1.y * y0.y + x1.z * y0.z + x1.w * y0.w;
      a11 += x1.x * y1.x + x1.y * y1.y + x1.z * y1.z + x1.w * y1.w;
    }
  }
  int c0 = ct * 32 + ox;
  if (!isQ) {
    int row0 = rt * 32 + oy;
    K2[(size_t)row0 * 512 + c0]           = a00 + 64.f * bk[c0];
    K2[(size_t)row0 * 512 + c0 + 1]       = a01 + 64.f * bk[c0 + 1];
    K2[(size_t)(row0 + 1) * 512 + c0]     = a10 + 64.f * bk[c0];
    K2[(size_t)(row0 + 1) * 512 + c0 + 1] = a11 + 64.f * bk[c0 + 1];
  } else if (oy < 8) {
    const float scale = 0.125f;
    qs[(size_t)oy * 512 + c0]           = (a00 + bq[c0]) * scale;
    qs[(size_t)oy * 512 + c0 + 1]       = (a01 + bq[c0 + 1]) * scale;
    qs[(size_t)(oy + 1) * 512 + c0]     = (a10 + bq[c0]) * scale;
    qs[(size_t)(oy + 1) * 512 + c0 + 1] = (a11 + bq[c0 + 1]) * scale;
  }
}

// ---------------- kernel 4: fused V-GEMM x2 slabs + softmax + PV -------------
// grid 256 = slab-pair(32) * g(8), XCD-grouped; 512 threads = 8 waves, w = e.
// LDS 128KB: Xa [8 kc][64 dd][128B] @0, Xb @64KB — staged from two contiguous
// 64KB XTg regions. K-loop: 32 MFMA/step, shared af, depth-2 prefetch.
// Vp overlays dead X-tiles after the loop.
__global__ __launch_bounds__(512, 2) void k_fused(
    const unsigned short* __restrict__ XT, const unsigned short* __restrict__ Wvb,
    const float* __restrict__ K2, const float* __restrict__ qs,
    const float* __restrict__ bv, float* __restrict__ out) {
  int p = blockIdx.x;
  int xcd = p & 7, idx = p >> 3;              // idx in [0,32)
  int sp = xcd * 4 + (idx & 3);               // slab pair [0,32)
  int g = idx >> 2;                           // [0,8)
  int slab0 = sp * 2, slab1 = slab0 + 1;
  int b = sp >> 2;
  int n0 = slab0 & 7, n1 = slab1 & 7;

  int tid = threadIdx.x;
  int w = tid >> 6, l = tid & 63;
  int l15 = l & 15, l4 = l >> 4, lr = l >> 3, lc = l & 7;

  __shared__ __align__(16) unsigned char smem[131072];

  const unsigned swzel = (unsigned)((lc ^ lr) << 3);  // pre-swizzled src col
  // g-blocked XT: contiguous 64KB region per (slab,g)
  const unsigned short* xsrc0 = XT + (size_t)slab0 * 262144 + (size_t)g * 32768;
  const unsigned short* xsrc1 = XT + (size_t)slab1 * 262144 + (size_t)g * 32768;
  const unsigned short* wbase = Wvb + (size_t)(w * 64 + l15) * 512 + l4 * 8;
  const int drow = w * 8 + lr;   // dd row this lane stages

  // ---- stage both X-tiles: 16 x global_load_lds (16B) per thread ----
#pragma unroll
  for (int i = 0; i < 8; ++i)
    gload16(xsrc0 + (size_t)drow * 512 + i * 64 + swzel,
            smem + i * 8192 + w * 1024);
#pragma unroll
  for (int i = 0; i < 8; ++i)
    gload16(xsrc1 + (size_t)drow * 512 + i * 64 + swzel,
            smem + 65536 + i * 8192 + w * 1024);

  float alpha = qs[(size_t)b * 512 + w * 64 + l];               // lane = qq
  float beta0 = K2[(size_t)(slab0 * 8 + g) * 512 + w * 64 + l]; // lane = kk
  float beta1 = K2[(size_t)(slab1 * 8 + g) * 512 + w * 64 + l];
  float bvreg = bv[w * 64 + l];                                 // lane = kk

  f32x4_t acc0[4][4], acc1[4][4];
#pragma unroll
  for (int i = 0; i < 4; ++i)
#pragma unroll
    for (int j = 0; j < 4; ++j) {
      acc0[i][j] = (f32x4_t){0.f, 0.f, 0.f, 0.f};
      acc1[i][j] = (f32x4_t){0.f, 0.f, 0.f, 0.f};
    }

  __syncthreads();   // both tiles resident for the whole K-loop

  // ---- interleaved K-loop: 16 steps, 32 MFMA/step, shared af, depth-2 ----
  bf16x8_t af[2][4];
#pragma unroll
  for (int mt = 0; mt < 4; ++mt)
    af[0][mt] = *(const bf16x8_t*)(wbase + mt * 16 * 512);

#pragma unroll
  for (int s = 0; s < 16; ++s) {
    if (s < 15) {
#pragma unroll
      for (int mt = 0; mt < 4; ++mt)
        af[(s + 1) & 1][mt] =
            *(const bf16x8_t*)(wbase + mt * 16 * 512 + (s + 1) * 32);
    }
    unsigned colx = (unsigned)((s & 1) * 64 + l4 * 16);
    unsigned char* Ba = smem + (s >> 1) * 8192;
    unsigned char* Bb = smem + 65536 + (s >> 1) * 8192;
    bf16x8_t b0[4], b1[4];
#pragma unroll
    for (int nt = 0; nt < 4; ++nt) {
      unsigned row = (unsigned)(nt * 16 + l15);
      unsigned off = row * 128 + (colx ^ ((row & 7) << 4));
      b0[nt] = *(const bf16x8_t*)(Ba + off);
      b1[nt] = *(const bf16x8_t*)(Bb + off);
    }
#pragma unroll
    for (int mt = 0; mt < 4; ++mt)
#pragma unroll
      for (int nt = 0; nt < 4; ++nt)
        acc0[mt][nt] = __builtin_amdgcn_mfma_f32_16x16x32_bf16(
            af[s & 1][mt], b0[nt], acc0[mt][nt], 0, 0, 0);
#pragma unroll
    for (int mt = 0; mt < 4; ++mt)
#pragma unroll
      for (int nt = 0; nt < 4; ++nt)
        acc1[mt][nt] = __builtin_amdgcn_mfma_f32_16x16x32_bf16(
            af[s & 1][mt], b1[nt], acc1[mt][nt], 0, 0, 0);
  }

  __syncthreads();   // all waves done reading both X-tiles; safe to overlay

  // ---- per-slab: spill V -> wave-private LDS, softmax, PV, store ----
  // acc[mt][nt] reg r: kk = mt*16 + l4*4 + r, dd = nt*16 + l15.
#define SLAB_TAIL(ACC, VPOFF, BETA, NN)                                        \
  do {                                                                         \
    unsigned char* Vp = smem + (VPOFF) + w * 8192;                             \
    _Pragma("unroll")                                                          \
    for (int mt = 0; mt < 4; ++mt) {                                           \
      float bq0 = __shfl(bvreg, mt * 16 + l4 * 4 + 0);                         \
      float bq1 = __shfl(bvreg, mt * 16 + l4 * 4 + 1);                         \
      float bq2 = __shfl(bvreg, mt * 16 + l4 * 4 + 2);                         \
      float bq3 = __shfl(bvreg, mt * 16 + l4 * 4 + 3);                         \
      _Pragma("unroll")                                                        \
      for (int nt = 0; nt < 4; ++nt) {                                         \
        unsigned dd = (unsigned)(nt * 16 + l15);                               \
        uint2 pk;                                                              \
        pk.x = (unsigned)f2bf(ACC[mt][nt][0] + bq0) |                          \
               ((unsigned)f2bf(ACC[mt][nt][1] + bq1) << 16);                   \
        pk.y = (unsigned)f2bf(ACC[mt][nt][2] + bq2) |                          \
               ((unsigned)f2bf(ACC[mt][nt][3] + bq3) << 16);                   \
        *(uint2*)(Vp + dd * 128 +                                              \
                  ((unsigned)(mt * 32 + l4 * 8) ^ ((dd & 7) << 4))) = pk;      \
      }                                                                        \
    }                                                                          \
    float bmax = (BETA), bmin = (BETA);                                        \
    _Pragma("unroll")                                                          \
    for (int o = 32; o >= 1; o >>= 1) {                                        \
      bmax = fmaxf(bmax, __shfl_xor(bmax, o));                                 \
      bmin = fminf(bmin, __shfl_xor(bmin, o));                                 \
    }                                                                          \
    float m = alpha >= 0.f ? alpha * bmax : alpha * bmin;                      \
    float ssum = 0.f;                                                          \
    _Pragma("unroll 8")                                                        \
    for (int kk = 0; kk < 64; ++kk)                                            \
      ssum += __expf(fmaf(alpha, __shfl((BETA), kk), -m));                     \
    float inv = 1.0f / ssum;                                                   \
    f32x4_t acc2[4][4];                                                        \
    _Pragma("unroll")                                                          \
    for (int i = 0; i < 4; ++i)                                                \
      _Pragma("unroll")                                                        \
      for (int j = 0; j < 4; ++j) acc2[i][j] = (f32x4_t){0.f, 0.f, 0.f, 0.f};  \
    _Pragma("unroll")                                                          \
    for (int ks = 0; ks < 2; ++ks) {                                           \
      bf16x8_t va[4];                                                          \
      _Pragma("unroll")                                                        \
      for (int mt = 0; mt < 4; ++mt) {                                         \
        unsigned dd = (unsigned)(mt * 16 + l15);                               \
        va[mt] = *(const bf16x8_t*)(Vp + dd * 128 +                            \
                  ((unsigned)(ks * 64 + l4 * 16) ^ ((dd & 7) << 4)));          \
      }                                                                        \
      float bvv[8];                                                            \
      _Pragma("unroll")                                                        \
      for (int i = 0; i < 8; ++i)                                              \
        bvv[i] = __shfl((BETA), ks * 32 + l4 * 8 + i);                         \
      bf16x8_t pb[4];                                                          \
      _Pragma("unroll")                                                        \
      for (int nt = 0; nt < 4; ++nt) {                                         \
        int qq = nt * 16 + l15;                                                \
        float aq = __shfl(alpha, qq);                                          \
        float mq = __shfl(m, qq);                                              \
        float iq = __shfl(inv, qq);                                            \
        bf16x8_t pp;                                                           \
        _Pragma("unroll")                                                      \
        for (int i = 0; i < 8; ++i)                                            \
          pp[i] = (short)f2bf(__expf(fmaf(aq, bvv[i], -mq)) * iq);             \
        pb[nt] = pp;                                                           \
      }                                                                        \
      _Pragma("unroll")                                                        \
      for (int mt = 0; mt < 4; ++mt)                                           \
        _Pragma("unroll")                                                      \
        for (int nt = 0; nt < 4; ++nt)                                         \
          acc2[mt][nt] = __builtin_amdgcn_mfma_f32_16x16x32_bf16(              \
              va[mt], pb[nt], acc2[mt][nt], 0, 0, 0);                          \
    }                                                                          \
    _Pragma("unroll")                                                          \
    for (int mt = 0; mt < 4; ++mt) {                                           \
      _Pragma("unroll")                                                        \
      for (int r = 0; r < 4; ++r) {                                            \
        int dd = mt * 16 + l4 * 4 + r;                                         \
        size_t base =                                                          \
            (((size_t)(b * 512 + (NN) * 64 + dd)) * 64 + (g * 8 + w)) * 64;    \
        _Pragma("unroll")                                                      \
        for (int nt = 0; nt < 4; ++nt)                                         \
          out[base + nt * 16 + l15] = acc2[mt][nt][r];                         \
      }                                                                        \
    }                                                                          \
  } while (0)

  SLAB_TAIL(acc0, 0, beta0, n0);
  SLAB_TAIL(acc1, 65536, beta1, n1);
#undef SLAB_TAIL
}

// ---------------------------------------------------------------------------
extern "C" void kernel_launch(void* const* d_in, const int* in_sizes, int n_in,
                              void* d_out, int out_size, void* d_ws, size_t ws_size,
                              hipStream_t stream) {
  const float* guide = (const float*)d_in[0];
  const float* hid   = (const float*)d_in[1];
  const float* Wq    = (const float*)d_in[2];
  const float* bq    = (const float*)d_in[3];
  const float* Wk    = (const float*)d_in[4];
  const float* bk    = (const float*)d_in[5];
  const float* Wv    = (const float*)d_in[6];
  const float* bv    = (const float*)d_in[7];
  float* out = (float*)d_out;

  char* ws = (char*)d_ws;
  unsigned short* XT  = (unsigned short*)(ws);             // 33,554,432 B (g-blocked)
  unsigned short* Wvb = (unsigned short*)(ws + 33554432);  //    524,288 B
  float* hrsum        = (float*)(ws + 34078720);           //  1,048,576 B
  float* K2           = (float*)(ws + 35127296);           //  1,048,576 B
  float* qs           = (float*)(ws + 36175872);           //     16,384 B

  k_trans<<<1040, 256, 0, stream>>>(hid, XT, hrsum, Wv, Wvb);
  k_k2<<<272, 256, 0, stream>>>(hrsum, Wk, bk, guide, Wq, bq, K2, qs);
  k_fused<<<256, 512, 0, stream>>>(XT, Wvb, K2, qs, bv, out);
}

// Round 15
// 84.146 us; speedup vs baseline: 9.2130x; 1.0074x over previous
//
#include <hip/hip_runtime.h>
#include <hip/hip_bf16.h>
#include <stdint.h>

// ---------------------------------------------------------------------------
// MultiHeadCrossAttention, B=8 C=512 H=W=64 nh=8 d=64.
// Index algebra (t = h*64+w, f = t*512+c):
//   n = h>>3 (the HEAD), dd = (h&7)*8 + (w>>3), hh = (w&7)*8 + (c>>6), ww = c&63
// With e = hh&7, g = hh>>3: token j within slab (b,n): j = 8*dd + g.
// q broadcast over tokens -> scores rank-1:
//   scores[qq,kk] = qs[b][e*64+qq] * K2[b,n,g][e*64+kk]
//   qs = (guide@Wq^T + bq)*0.125 ; K2 = hrsum@Wk^T + 64*bk
//   hrsum[b,n,g,c'] = sum_{j==g mod 8} hid[b,c',n*512+j]
// attended[qq,dd] = sum_kk P[qq,kk] * V[e*64+kk][j(dd,g)]
//   V[c][j] = sum_c' Wv[c][c'] * hid[b][c'][n*512+j] + bv[c]
// out[b][n*64+dd][g*8+e][qq]
//
// r14 = r10 (best total, 84.2us) + G-BLOCKED XT: XTg[slab][g][dd 64][c' 512]
// (same bytes, permuted rows). k_fused's 128KB staging becomes two contiguous
// 64KB regions (was 64 rows strided 8KB over 1MB) -> better DRAM/L2 locality
// on the latency-exposed staging drain. LDS content identical (rows were
// already dd-ordered); all downstream math untouched.
// ---------------------------------------------------------------------------

typedef __attribute__((ext_vector_type(8))) short bf16x8_t;
typedef __attribute__((ext_vector_type(4))) float f32x4_t;

__device__ __forceinline__ unsigned short f2bf(float f) {
  unsigned int u = __float_as_uint(f);
  u += 0x7FFFu + ((u >> 16) & 1u);
  return (unsigned short)(u >> 16);
}

__device__ __forceinline__ void gload16(const void* g, void* lds) {
  __builtin_amdgcn_global_load_lds(
      (const __attribute__((address_space(1))) unsigned int*)g,
      (__attribute__((address_space(3))) unsigned int*)lds, 16, 0, 0);
}

// ---------------- kernel 2: transpose hid -> XTg (bf16) + hrsum (fp32) ------
// blocks [0,1024): (b,n,cb,rhalf) -> 32 c' rows x 512 j. [1024,1040): Wv cvt.
__global__ __launch_bounds__(256) void k_trans(const float* __restrict__ hid,
                                               unsigned short* __restrict__ XT,
                                               float* __restrict__ hrsum,
                                               const float* __restrict__ Wv,
                                               unsigned short* __restrict__ Wvb) {
  int bid = blockIdx.x;
  int tid = threadIdx.x;
  if (bid >= 1024) {
    int blk = bid - 1024;
#pragma unroll
    for (int i = 0; i < 16; ++i) {
      int idx = blk * 4096 + i * 256 + tid;
      float4 v = ((const float4*)Wv)[idx];
      ushort4 o;
      o.x = f2bf(v.x); o.y = f2bf(v.y); o.z = f2bf(v.z); o.w = f2bf(v.w);
      ((ushort4*)Wvb)[idx] = o;
    }
    return;
  }
  int rh = bid & 1, cb = (bid >> 1) & 7, n = (bid >> 4) & 7, b = bid >> 7;
  __shared__ float T[32][65];
  __shared__ float hsred[32][8];
  ((float*)hsred)[tid] = 0.f;

  float part[2][4];
#pragma unroll
  for (int m = 0; m < 2; ++m)
#pragma unroll
    for (int i = 0; i < 4; ++i) part[m][i] = 0.f;

  const int f4 = tid & 15;
  const int r0 = tid >> 4;
  const float* srcbase = hid + (size_t)(b * 512 + cb * 64 + rh * 32) * 4096 + n * 512;
  // g-blocked XT: XTg[slab][g][dd][c']; this block owns c' = cb*64+rh*32+[0,32)
  unsigned short* xtbase =
      XT + (size_t)(b * 8 + n) * 262144 + cb * 64 + rh * 32;

  float4 va[2], vb2[2];
#pragma unroll
  for (int m = 0; m < 2; ++m)
    va[m] = *(const float4*)(srcbase + (size_t)(r0 + 16 * m) * 4096 + f4 * 4);

#define TSTEP(JC, CUR, NXT, LAST)                                              \
  do {                                                                         \
    _Pragma("unroll")                                                          \
    for (int m_ = 0; m_ < 2; ++m_) {                                           \
      int r_ = r0 + 16 * m_;                                                   \
      T[r_][f4 * 4 + 0] = CUR[m_].x;  T[r_][f4 * 4 + 1] = CUR[m_].y;           \
      T[r_][f4 * 4 + 2] = CUR[m_].z;  T[r_][f4 * 4 + 3] = CUR[m_].w;           \
      part[m_][0] += CUR[m_].x; part[m_][1] += CUR[m_].y;                      \
      part[m_][2] += CUR[m_].z; part[m_][3] += CUR[m_].w;                      \
    }                                                                          \
    if (!(LAST)) {                                                             \
      _Pragma("unroll")                                                        \
      for (int m_ = 0; m_ < 2; ++m_)                                           \
        NXT[m_] = *(const float4*)(srcbase + (size_t)(r0 + 16 * m_) * 4096 +   \
                                   ((JC) + 1) * 64 + f4 * 4);                  \
    }                                                                          \
    __syncthreads();                                                           \
    {                                                                          \
      int jl_ = tid >> 2, o_ = tid & 3;                                        \
      unsigned short t0 = f2bf(T[o_ * 8 + 0][jl_]);                            \
      unsigned short t1 = f2bf(T[o_ * 8 + 1][jl_]);                            \
      unsigned short t2 = f2bf(T[o_ * 8 + 2][jl_]);                            \
      unsigned short t3 = f2bf(T[o_ * 8 + 3][jl_]);                            \
      unsigned short t4 = f2bf(T[o_ * 8 + 4][jl_]);                            \
      unsigned short t5 = f2bf(T[o_ * 8 + 5][jl_]);                            \
      unsigned short t6 = f2bf(T[o_ * 8 + 6][jl_]);                            \
      unsigned short t7 = f2bf(T[o_ * 8 + 7][jl_]);                            \
      uint4 pk_;                                                               \
      pk_.x = (unsigned)t0 | ((unsigned)t1 << 16);                             \
      pk_.y = (unsigned)t2 | ((unsigned)t3 << 16);                             \
      pk_.z = (unsigned)t4 | ((unsigned)t5 << 16);                             \
      pk_.w = (unsigned)t6 | ((unsigned)t7 << 16);                             \
      int g_ = jl_ & 7;                                                        \
      int dd_ = (JC) * 8 + (jl_ >> 3);                                         \
      *(uint4*)(xtbase + (size_t)g_ * 32768 + (size_t)dd_ * 512 + o_ * 8) =    \
          pk_;                                                                 \
    }                                                                          \
    __syncthreads();                                                           \
  } while (0)

  TSTEP(0, va, vb2, 0);
  TSTEP(1, vb2, va, 0);
  TSTEP(2, va, vb2, 0);
  TSTEP(3, vb2, va, 0);
  TSTEP(4, va, vb2, 0);
  TSTEP(5, vb2, va, 0);
  TSTEP(6, va, vb2, 0);
  TSTEP(7, vb2, va, 1);
#undef TSTEP

  {
    int gbase = (f4 & 1) * 4;
#pragma unroll
    for (int m = 0; m < 2; ++m) {
      int r = r0 + 16 * m;
#pragma unroll
      for (int i = 0; i < 4; ++i) atomicAdd(&hsred[r][gbase + i], part[m][i]);
    }
  }
  __syncthreads();
  float* hout = hrsum + (size_t)(b * 8 + n) * 4096 + cb * 64 + rh * 32;
  {
    int g = tid >> 5, r = tid & 31;
    hout[(size_t)g * 512 + r] = hsred[r][g];
  }
}

// ---------------- kernel 3: K2 = hrsum@Wk^T + 64*bk ; qs = (guide@Wq^T+bq)/8 -
__global__ __launch_bounds__(256) void k_k2(const float* __restrict__ hrsum,
                                            const float* __restrict__ Wk,
                                            const float* __restrict__ bk,
                                            const float* __restrict__ guide,
                                            const float* __restrict__ Wq,
                                            const float* __restrict__ bq,
                                            float* __restrict__ K2,
                                            float* __restrict__ qs) {
  int bid = blockIdx.x;
  int rt = bid >> 4, ct = bid & 15;
  bool isQ = (rt == 16);
  const float* A = isQ ? guide : (hrsum + (size_t)rt * 32 * 512);
  const float* Bm = isQ ? Wq : Wk;
  int arows = isQ ? 8 : 32;
  int tid = threadIdx.x;
  __shared__ float Ah[32][36];
  __shared__ float Bh[32][36];
  int r = tid >> 3, f = tid & 7;
  int oy = (tid >> 4) * 2, ox = (tid & 15) * 2;
  float a00 = 0.f, a01 = 0.f, a10 = 0.f, a11 = 0.f;

  for (int kc = 0; kc < 16; ++kc) {
    __syncthreads();
    float4 av = (r < arows) ? *(const float4*)(A + (size_t)r * 512 + kc * 32 + f * 4)
                            : make_float4(0.f, 0.f, 0.f, 0.f);
    *(float4*)(&Ah[r][f * 4]) = av;
    float4 bv = *(const float4*)(Bm + (size_t)(ct * 32 + r) * 512 + kc * 32 + f * 4);
    *(float4*)(&Bh[r][f * 4]) = bv;
    __syncthreads();
#pragma unroll
    for (int kk = 0; kk < 32; kk += 4) {
      float4 x0 = *(float4*)(&Ah[oy][kk]);
      float4 x1 = *(float4*)(&Ah[oy + 1][kk]);
      float4 y0 = *(float4*)(&Bh[ox][kk]);
      float4 y1 = *(float4*)(&Bh[ox + 1][kk]);
      a00 += x0.x * y0.x + x0.y * y0.y + x0.z * y0.z + x0.w * y0.w;
      a01 += x0.x * y1.x + x0.y * y1.y + x0.z * y1.z + x0.w * y1.w;
      a10 += x1.x * y0.x + x1.y * y0.y + x1.z * y0.z + x1.w * y0.w;
      a11 += x1.x * y1.x + x1.y * y1.y + x1.z * y1.z + x1.w * y1.w;
    }
  }
  int c0 = ct * 32 + ox;
  if (!isQ) {
    int row0 = rt * 32 + oy;
    K2[(size_t)row0 * 512 + c0]           = a00 + 64.f * bk[c0];
    K2[(size_t)row0 * 512 + c0 + 1]       = a01 + 64.f * bk[c0 + 1];
    K2[(size_t)(row0 + 1) * 512 + c0]     = a10 + 64.f * bk[c0];
    K2[(size_t)(row0 + 1) * 512 + c0 + 1] = a11 + 64.f * bk[c0 + 1];
  } else if (oy < 8) {
    const float scale = 0.125f;
    qs[(size_t)oy * 512 + c0]           = (a00 + bq[c0]) * scale;
    qs[(size_t)oy * 512 + c0 + 1]       = (a01 + bq[c0 + 1]) * scale;
    qs[(size_t)(oy + 1) * 512 + c0]     = (a10 + bq[c0]) * scale;
    qs[(size_t)(oy + 1) * 512 + c0 + 1] = (a11 + bq[c0 + 1]) * scale;
  }
}

// ---------------- kernel 4: fused V-GEMM x2 slabs + softmax + PV -------------
// grid 256 = slab-pair(32) * g(8), XCD-grouped; 512 threads = 8 waves, w = e.
// LDS 128KB: Xa [8 kc][64 dd][128B] @0, Xb @64KB — staged from two contiguous
// 64KB XTg regions. K-loop: 32 MFMA/step, shared af, depth-2 prefetch.
// Vp overlays dead X-tiles after the loop.
__global__ __launch_bounds__(512, 2) void k_fused(
    const unsigned short* __restrict__ XT, const unsigned short* __restrict__ Wvb,
    const float* __restrict__ K2, const float* __restrict__ qs,
    const float* __restrict__ bv, float* __restrict__ out) {
  int p = blockIdx.x;
  int xcd = p & 7, idx = p >> 3;              // idx in [0,32)
  int sp = xcd * 4 + (idx & 3);               // slab pair [0,32)
  int g = idx >> 2;                           // [0,8)
  int slab0 = sp * 2, slab1 = slab0 + 1;
  int b = sp >> 2;
  int n0 = slab0 & 7, n1 = slab1 & 7;

  int tid = threadIdx.x;
  int w = tid >> 6, l = tid & 63;
  int l15 = l & 15, l4 = l >> 4, lr = l >> 3, lc = l & 7;

  __shared__ __align__(16) unsigned char smem[131072];

  const unsigned swzel = (unsigned)((lc ^ lr) << 3);  // pre-swizzled src col
  // g-blocked XT: contiguous 64KB region per (slab,g)
  const unsigned short* xsrc0 = XT + (size_t)slab0 * 262144 + (size_t)g * 32768;
  const unsigned short* xsrc1 = XT + (size_t)slab1 * 262144 + (size_t)g * 32768;
  const unsigned short* wbase = Wvb + (size_t)(w * 64 + l15) * 512 + l4 * 8;
  const int drow = w * 8 + lr;   // dd row this lane stages

  // ---- stage both X-tiles: 16 x global_load_lds (16B) per thread ----
#pragma unroll
  for (int i = 0; i < 8; ++i)
    gload16(xsrc0 + (size_t)drow * 512 + i * 64 + swzel,
            smem + i * 8192 + w * 1024);
#pragma unroll
  for (int i = 0; i < 8; ++i)
    gload16(xsrc1 + (size_t)drow * 512 + i * 64 + swzel,
            smem + 65536 + i * 8192 + w * 1024);

  float alpha = qs[(size_t)b * 512 + w * 64 + l];               // lane = qq
  float beta0 = K2[(size_t)(slab0 * 8 + g) * 512 + w * 64 + l]; // lane = kk
  float beta1 = K2[(size_t)(slab1 * 8 + g) * 512 + w * 64 + l];
  float bvreg = bv[w * 64 + l];                                 // lane = kk

  f32x4_t acc0[4][4], acc1[4][4];
#pragma unroll
  for (int i = 0; i < 4; ++i)
#pragma unroll
    for (int j = 0; j < 4; ++j) {
      acc0[i][j] = (f32x4_t){0.f, 0.f, 0.f, 0.f};
      acc1[i][j] = (f32x4_t){0.f, 0.f, 0.f, 0.f};
    }

  __syncthreads();   // both tiles resident for the whole K-loop

  // ---- interleaved K-loop: 16 steps, 32 MFMA/step, shared af, depth-2 ----
  bf16x8_t af[2][4];
#pragma unroll
  for (int mt = 0; mt < 4; ++mt)
    af[0][mt] = *(const bf16x8_t*)(wbase + mt * 16 * 512);

#pragma unroll
  for (int s = 0; s < 16; ++s) {
    if (s < 15) {
#pragma unroll
      for (int mt = 0; mt < 4; ++mt)
        af[(s + 1) & 1][mt] =
            *(const bf16x8_t*)(wbase + mt * 16 * 512 + (s + 1) * 32);
    }
    unsigned colx = (unsigned)((s & 1) * 64 + l4 * 16);
    unsigned char* Ba = smem + (s >> 1) * 8192;
    unsigned char* Bb = smem + 65536 + (s >> 1) * 8192;
    bf16x8_t b0[4], b1[4];
#pragma unroll
    for (int nt = 0; nt < 4; ++nt) {
      unsigned row = (unsigned)(nt * 16 + l15);
      unsigned off = row * 128 + (colx ^ ((row & 7) << 4));
      b0[nt] = *(const bf16x8_t*)(Ba + off);
      b1[nt] = *(const bf16x8_t*)(Bb + off);
    }
#pragma unroll
    for (int mt = 0; mt < 4; ++mt)
#pragma unroll
      for (int nt = 0; nt < 4; ++nt)
        acc0[mt][nt] = __builtin_amdgcn_mfma_f32_16x16x32_bf16(
            af[s & 1][mt], b0[nt], acc0[mt][nt], 0, 0, 0);
#pragma unroll
    for (int mt = 0; mt < 4; ++mt)
#pragma unroll
      for (int nt = 0; nt < 4; ++nt)
        acc1[mt][nt] = __builtin_amdgcn_mfma_f32_16x16x32_bf16(
            af[s & 1][mt], b1[nt], acc1[mt][nt], 0, 0, 0);
  }

  __syncthreads();   // all waves done reading both X-tiles; safe to overlay

  // ---- per-slab: spill V -> wave-private LDS, softmax, PV, store ----
  // acc[mt][nt] reg r: kk = mt*16 + l4*4 + r, dd = nt*16 + l15.
#define SLAB_TAIL(ACC, VPOFF, BETA, NN)                                        \
  do {                                                                         \
    unsigned char* Vp = smem + (VPOFF) + w * 8192;                             \
    _Pragma("unroll")                                                          \
    for (int mt = 0; mt < 4; ++mt) {                                           \
      float bq0 = __shfl(bvreg, mt * 16 + l4 * 4 + 0);                         \
      float bq1 = __shfl(bvreg, mt * 16 + l4 * 4 + 1);                         \
      float bq2 = __shfl(bvreg, mt * 16 + l4 * 4 + 2);                         \
      float bq3 = __shfl(bvreg, mt * 16 + l4 * 4 + 3);                         \
      _Pragma("unroll")                                                        \
      for (int nt = 0; nt < 4; ++nt) {                                         \
        unsigned dd = (unsigned)(nt * 16 + l15);                               \
        uint2 pk;                                                              \
        pk.x = (unsigned)f2bf(ACC[mt][nt][0] + bq0) |                          \
               ((unsigned)f2bf(ACC[mt][nt][1] + bq1) << 16);                   \
        pk.y = (unsigned)f2bf(ACC[mt][nt][2] + bq2) |                          \
               ((unsigned)f2bf(ACC[mt][nt][3] + bq3) << 16);                   \
        *(uint2*)(Vp + dd * 128 +                                              \
                  ((unsigned)(mt * 32 + l4 * 8) ^ ((dd & 7) << 4))) = pk;      \
      }                                                                        \
    }                                                                          \
    float bmax = (BETA), bmin = (BETA);                                        \
    _Pragma("unroll")                                                          \
    for (int o = 32; o >= 1; o >>= 1) {                                        \
      bmax = fmaxf(bmax, __shfl_xor(bmax, o));                                 \
      bmin = fminf(bmin, __shfl_xor(bmin, o));                                 \
    }                                                                          \
    float m = alpha >= 0.f ? alpha * bmax : alpha * bmin;                      \
    float ssum = 0.f;                                                          \
    _Pragma("unroll 8")                                                        \
    for (int kk = 0; kk < 64; ++kk)                                            \
      ssum += __expf(fmaf(alpha, __shfl((BETA), kk), -m));                     \
    float inv = 1.0f / ssum;                                                   \
    f32x4_t acc2[4][4];                                                        \
    _Pragma("unroll")                                                          \
    for (int i = 0; i < 4; ++i)                                                \
      _Pragma("unroll")                                                        \
      for (int j = 0; j < 4; ++j) acc2[i][j] = (f32x4_t){0.f, 0.f, 0.f, 0.f};  \
    _Pragma("unroll")                                                          \
    for (int ks = 0; ks < 2; ++ks) {                                           \
      bf16x8_t va[4];                                                          \
      _Pragma("unroll")                                                        \
      for (int mt = 0; mt < 4; ++mt) {                                         \
        unsigned dd = (unsigned)(mt * 16 + l15);                               \
        va[mt] = *(const bf16x8_t*)(Vp + dd * 128 +                            \
                  ((unsigned)(ks * 64 + l4 * 16) ^ ((dd & 7) << 4)));          \
      }                                                                        \
      float bvv[8];                                                            \
      _Pragma("unroll")                                                        \
      for (int i = 0; i < 8; ++i)                                              \
        bvv[i] = __shfl((BETA), ks * 32 + l4 * 8 + i);                         \
      bf16x8_t pb[4];                                                          \
      _Pragma("unroll")                                                        \
      for (int nt = 0; nt < 4; ++nt) {                                         \
        int qq = nt * 16 + l15;                                                \
        float aq = __shfl(alpha, qq);                                          \
        float mq = __shfl(m, qq);                                              \
        float iq = __shfl(inv, qq);                                            \
        bf16x8_t pp;                                                           \
        _Pragma("unroll")                                                      \
        for (int i = 0; i < 8; ++i)                                            \
          pp[i] = (short)f2bf(__expf(fmaf(aq, bvv[i], -mq)) * iq);             \
        pb[nt] = pp;                                                           \
      }                                                                        \
      _Pragma("unroll")                                                        \
      for (int mt = 0; mt < 4; ++mt)                                           \
        _Pragma("unroll")                                                      \
        for (int nt = 0; nt < 4; ++nt)                                         \
          acc2[mt][nt] = __builtin_amdgcn_mfma_f32_16x16x32_bf16(              \
              va[mt], pb[nt], acc2[mt][nt], 0, 0, 0);                          \
    }                                                                          \
    _Pragma("unroll")                                                          \
    for (int mt = 0; mt < 4; ++mt) {                                           \
      _Pragma("unroll")                                                        \
      for (int r = 0; r < 4; ++r) {                                            \
        int dd = mt * 16 + l4 * 4 + r;                                         \
        size_t base =                                                          \
            (((size_t)(b * 512 + (NN) * 64 + dd)) * 64 + (g * 8 + w)) * 64;    \
        _Pragma("unroll")                                                      \
        for (int nt = 0; nt < 4; ++nt)                                         \
          out[base + nt * 16 + l15] = acc2[mt][nt][r];                         \
      }                                                                        \
    }                                                                          \
  } while (0)

  SLAB_TAIL(acc0, 0, beta0, n0);
  SLAB_TAIL(acc1, 65536, beta1, n1);
#undef SLAB_TAIL
}

// ---------------------------------------------------------------------------
extern "C" void kernel_launch(void* const* d_in, const int* in_sizes, int n_in,
                              void* d_out, int out_size, void* d_ws, size_t ws_size,
                              hipStream_t stream) {
  const float* guide = (const float*)d_in[0];
  const float* hid   = (const float*)d_in[1];
  const float* Wq    = (const float*)d_in[2];
  const float* bq    = (const float*)d_in[3];
  const float* Wk    = (const float*)d_in[4];
  const float* bk    = (const float*)d_in[5];
  const float* Wv    = (const float*)d_in[6];
  const float* bv    = (const float*)d_in[7];
  float* out = (float*)d_out;

  char* ws = (char*)d_ws;
  unsigned short* XT  = (unsigned short*)(ws);             // 33,554,432 B (g-blocked)
  unsigned short* Wvb = (unsigned short*)(ws + 33554432);  //    524,288 B
  float* hrsum        = (float*)(ws + 34078720);           //  1,048,576 B
  float* K2           = (float*)(ws + 35127296);           //  1,048,576 B
  float* qs           = (float*)(ws + 36175872);           //     16,384 B

  k_trans<<<1040, 256, 0, stream>>>(hid, XT, hrsum, Wv, Wvb);
  k_k2<<<272, 256, 0, stream>>>(hrsum, Wk, bk, guide, Wq, bq, K2, qs);
  k_fused<<<256, 512, 0, stream>>>(XT, Wvb, K2, qs, bv, out);
}